// Round 9
// baseline (214.999 us; speedup 1.0000x reference)
//
#include <hip/hip_runtime.h>

// GHM-C loss, two-pass: counts -> weighted sum -> tiny reduce.
// loss = sum_elem bce/(C_bin(elem) * n_nonempty);  weights need GLOBAL counts.
//
// R1: same-address device atomics -> cross-XCD bouncing -> per-block partials.
// R3: per-elem LDS RMW hist = 123us (latency).  R5: register select tree = 76us.
// R6: FAILED ticket fusion (2048 same-line atomics tail).
// R7/R8: ILP/fence attempts neutral; L2-warm replays SAME speed -> not memory.
// R9: exec-mask tree neutral (exec hazards). R10: native-trans builtins -> bitwise
//   IDENTICAL output (absmax 0.0) -> __expf/__logf were already native. Theory dead.
// R11 (this round): the 10-way select tree (30 of ~50 instr/elem) exists only
//   because one pass must keep 10 sums. Split passes:
//   A: counts only (~14 instr/elem, no tree/softplus) -> expect memory-bound ~27us.
//      Doubles as stripped-body probe for the residual-stall mystery.
//   B: per-block count-reduce prologue (80KB from L2/L3) -> w[10] LDS table;
//      main loop: acc += wtab[bin]*bce  (tree -> 1 ds_read + 1 fmac).
//      Table reads span <=10 banks -> broadcast, conflict-free.
//   C: 1-block reduce of 2048 block partials (double).
//   No atomics, no memsets, no inline asm.

#define NBINS  10
#define GRID1  2048
#define BLOCK1 256

typedef float vf4 __attribute__((ext_vector_type(4)));
typedef int   vi4 __attribute__((ext_vector_type(4)));

#if __has_builtin(__builtin_amdgcn_exp2f)
__device__ __forceinline__ float nexp2(float a) { return __builtin_amdgcn_exp2f(a); }
#else
__device__ __forceinline__ float nexp2(float a) { return __expf(a * 0.69314718055994531f); }
#endif
#if __has_builtin(__builtin_amdgcn_logf)
__device__ __forceinline__ float nlog2(float a) { return __builtin_amdgcn_logf(a); }
#else
__device__ __forceinline__ float nlog2(float a) { return __logf(a) * 1.44269504088896341f; }
#endif

#define LOG2E 1.44269504088896341f
#define LN2   0.69314718055994531f

// ---------------- Pass A: per-block bin counts ----------------
__global__ __launch_bounds__(BLOCK1) void ghmc_counts(
    const vf4* __restrict__ pred4,
    const vi4* __restrict__ targ4,
    int* __restrict__ partial_c,     // [NBINS][GRID1] bin-major
    int nvec4)
{
    __shared__ int cred[BLOCK1 / 64][NBINS];

    unsigned long long cnt = 0;   // 10 x 6-bit packed counts; max 40/bin/thread < 63

    const int idx    = blockIdx.x * BLOCK1 + threadIdx.x;
    const int stride = GRID1 * BLOCK1;

    auto binof = [&](float x, int t) -> int {
        float tf = (float)t;
        float z  = __builtin_amdgcn_rcpf(1.0f + nexp2(-x * LOG2E));   // sigmoid(x)
        float g  = fabsf(z - tf);                                     // [0,1]
        int   bi = (int)(g * 10.0f);
        return bi > (NBINS - 1) ? (NBINS - 1) : bi;
    };

    int i = idx;
    for (; i + stride < nvec4; i += 2 * stride) {
        vf4 p0 = pred4[i];
        vi4 t0 = targ4[i];
        vf4 p1 = pred4[i + stride];
        vi4 t1 = targ4[i + stride];
        cnt += 1ull << (6 * binof(p0[0], t0[0]));
        cnt += 1ull << (6 * binof(p0[1], t0[1]));
        cnt += 1ull << (6 * binof(p0[2], t0[2]));
        cnt += 1ull << (6 * binof(p0[3], t0[3]));
        cnt += 1ull << (6 * binof(p1[0], t1[0]));
        cnt += 1ull << (6 * binof(p1[1], t1[1]));
        cnt += 1ull << (6 * binof(p1[2], t1[2]));
        cnt += 1ull << (6 * binof(p1[3], t1[3]));
    }
    if (i < nvec4) {
        vf4 p0 = pred4[i];
        vi4 t0 = targ4[i];
        cnt += 1ull << (6 * binof(p0[0], t0[0]));
        cnt += 1ull << (6 * binof(p0[1], t0[1]));
        cnt += 1ull << (6 * binof(p0[2], t0[2]));
        cnt += 1ull << (6 * binof(p0[3], t0[3]));
    }

    int c[NBINS];
#pragma unroll
    for (int b = 0; b < NBINS; ++b) c[b] = (int)((cnt >> (6 * b)) & 63ull);

#pragma unroll
    for (int b = 0; b < NBINS; ++b) {
#pragma unroll
        for (int off = 32; off > 0; off >>= 1)
            c[b] += __shfl_down(c[b], off, 64);
    }

    const int wave = threadIdx.x >> 6;
    if ((threadIdx.x & 63) == 0) {
#pragma unroll
        for (int b = 0; b < NBINS; ++b) cred[wave][b] = c[b];
    }
    __syncthreads();
    if (threadIdx.x < NBINS) {
        int b = threadIdx.x;
        partial_c[b * GRID1 + blockIdx.x] = cred[0][b] + cred[1][b] + cred[2][b] + cred[3][b];
    }
}

// ---------------- Pass B: weighted sum with LDS weight table ----------------
__global__ __launch_bounds__(BLOCK1) void ghmc_wsum(
    const vf4* __restrict__ pred4,
    const vi4* __restrict__ targ4,
    const int* __restrict__ partial_c,   // [NBINS][GRID1]
    float* __restrict__ partial_f,       // [GRID1]
    int nvec4)
{
    __shared__ int   credb[BLOCK1 / 64][NBINS];
    __shared__ int   ctot[NBINS];
    __shared__ float wtab[NBINS];
    __shared__ float fred[BLOCK1 / 64];

    // --- prologue: reduce global counts (redundant per block; 80KB from L2/L3) ---
    {
        int cb[NBINS];
#pragma unroll
        for (int b = 0; b < NBINS; ++b) cb[b] = 0;
        for (int k = threadIdx.x; k < GRID1; k += BLOCK1) {
#pragma unroll
            for (int b = 0; b < NBINS; ++b)
                cb[b] += partial_c[b * GRID1 + k];       // coalesced per bin
        }
#pragma unroll
        for (int b = 0; b < NBINS; ++b) {
#pragma unroll
            for (int off = 32; off > 0; off >>= 1)
                cb[b] += __shfl_down(cb[b], off, 64);
        }
        const int wave = threadIdx.x >> 6;
        if ((threadIdx.x & 63) == 0) {
#pragma unroll
            for (int b = 0; b < NBINS; ++b) credb[wave][b] = cb[b];
        }
        __syncthreads();
        if (threadIdx.x < NBINS) {
            int b = threadIdx.x;
            ctot[b] = credb[0][b] + credb[1][b] + credb[2][b] + credb[3][b];
        }
        __syncthreads();
        if (threadIdx.x < NBINS) {
            int nn = 0;
#pragma unroll
            for (int k = 0; k < NBINS; ++k) nn += (ctot[k] > 0) ? 1 : 0;
            int cb0 = ctot[threadIdx.x];
            // contrib per elem = bce / (C_b * nn); fold into one f32 weight
            wtab[threadIdx.x] = (cb0 > 0)
                ? (float)(1.0 / ((double)cb0 * (double)nn)) : 0.0f;
        }
        __syncthreads();
    }

    // --- main loop: acc += wtab[bin] * bce ---
    float acc = 0.0f;

    const int idx    = blockIdx.x * BLOCK1 + threadIdx.x;
    const int stride = GRID1 * BLOCK1;

    auto elem = [&](float x, int t) {
        float tf = (float)t;
        float z  = __builtin_amdgcn_rcpf(1.0f + nexp2(-x * LOG2E));   // sigmoid(x)
        float g  = fabsf(z - tf);
        int   bi = (int)(g * 10.0f);
        bi = bi > (NBINS - 1) ? (NBINS - 1) : bi;
        float sp = nlog2(1.0f + nexp2(z * LOG2E)) * LN2;              // softplus(z)
        float bce = sp - tf * z;
        acc += wtab[bi] * bce;                                        // 1 ds_read + 1 fmac
    };

    int i = idx;
    for (; i + stride < nvec4; i += 2 * stride) {
        vf4 p0 = pred4[i];
        vi4 t0 = targ4[i];
        vf4 p1 = pred4[i + stride];
        vi4 t1 = targ4[i + stride];
        elem(p0[0], t0[0]); elem(p0[1], t0[1]); elem(p0[2], t0[2]); elem(p0[3], t0[3]);
        elem(p1[0], t1[0]); elem(p1[1], t1[1]); elem(p1[2], t1[2]); elem(p1[3], t1[3]);
    }
    if (i < nvec4) {
        vf4 p0 = pred4[i];
        vi4 t0 = targ4[i];
        elem(p0[0], t0[0]); elem(p0[1], t0[1]); elem(p0[2], t0[2]); elem(p0[3], t0[3]);
    }

    // --- block reduction of acc ---
#pragma unroll
    for (int off = 32; off > 0; off >>= 1)
        acc += __shfl_down(acc, off, 64);
    const int wave = threadIdx.x >> 6;
    if ((threadIdx.x & 63) == 0) fred[wave] = acc;
    __syncthreads();
    if (threadIdx.x == 0)
        partial_f[blockIdx.x] = fred[0] + fred[1] + fred[2] + fred[3];
}

// ---------------- Pass C: final reduce ----------------
__global__ __launch_bounds__(BLOCK1) void ghmc_final(
    const float* __restrict__ partial_f,   // [GRID1]
    float* __restrict__ out,
    int nblocks)
{
    __shared__ double dred[BLOCK1 / 64];

    double a = 0.0;
    for (int j = threadIdx.x; j < nblocks; j += BLOCK1)
        a += (double)partial_f[j];

#pragma unroll
    for (int off = 32; off > 0; off >>= 1)
        a += __shfl_down(a, off, 64);

    const int wave = threadIdx.x >> 6;
    if ((threadIdx.x & 63) == 0) dred[wave] = a;
    __syncthreads();
    if (threadIdx.x == 0)
        out[0] = (float)(dred[0] + dred[1] + dred[2] + dred[3]);
}

extern "C" void kernel_launch(void* const* d_in, const int* in_sizes, int n_in,
                              void* d_out, int out_size, void* d_ws, size_t ws_size,
                              hipStream_t stream)
{
    const float* pred = (const float*)d_in[0];
    const int*   targ = (const int*)d_in[1];
    float*       out  = (float*)d_out;

    const int n     = in_sizes[0];   // 20,971,520 (divisible by 4)
    const int nvec4 = n / 4;

    int*   partial_c = (int*)d_ws;                                      // 80 KB
    float* partial_f = (float*)((char*)d_ws + NBINS * GRID1 * sizeof(int));  // 8 KB

    ghmc_counts<<<GRID1, BLOCK1, 0, stream>>>(
        (const vf4*)pred, (const vi4*)targ, partial_c, nvec4);

    ghmc_wsum<<<GRID1, BLOCK1, 0, stream>>>(
        (const vf4*)pred, (const vi4*)targ, partial_c, partial_f, nvec4);

    ghmc_final<<<1, BLOCK1, 0, stream>>>(partial_f, out, GRID1);
}